// Round 6
// baseline (105.248 us; speedup 1.0000x reference)
//
#include <hip/hip_runtime.h>
#include <math.h>

#define N_FFT 16384
#define HALF 8192
#define ROWS 1024    // B*Cin = B*Cout = 16*64
#define KS_A 64      // k-splits of the 8192 half-space
#define KR_A 128     // half-k per kA block

// ---------------- ws layout (float offsets) ----------------
// castab @0 [16384]
// casAp  @16384  [8192*64]  (perm cols: c<32 -> m=2c (even), c>=32 -> m=2(c-32)+1 (odd))
// casB   @540672 [64*8192]
// partial@1064960 [64*65536]
// xh     @5259264 [65536]
// lowT   @5324800 [65536]

__global__ __launch_bounds__(256) void k_tab(float* __restrict__ castab) {
    int i = blockIdx.x * 256 + threadIdx.x;
    if (i < N_FFT) {
        double ang = 6.283185307179586476925287 * (double)i / (double)N_FFT;
        castab[i] = (float)(cos(ang) + sin(ang));
    }
}

__global__ __launch_bounds__(256) void k_fill(const float* __restrict__ castab,
                                              float* __restrict__ casAp,
                                              float* __restrict__ casB) {
    int tid = blockIdx.x * 256 + threadIdx.x;    // 0 .. 2^20-1
    if (tid < (1 << 19)) {
        int n = tid >> 6, c = tid & 63;
        int m = (c < 32) ? (2 * c) : (2 * (c - 32) + 1);
        casAp[tid] = castab[(n * m) & (N_FFT - 1)];
    } else {
        int t2 = tid - (1 << 19);                // 0 .. 2^19-1
        int m = t2 >> 13, n = t2 & (HALF - 1);
        casB[t2] = castab[(m * n) & (N_FFT - 1)];
    }
}

// Step A (half-symmetric): for n<8192,
//   partial[ks][r][c] = sum_{k in split} (x[r][k] +- x[r][k+8192]) * casAp[k][c]
// grid 4096 = 64 rb * 64 ks; block 128 = 32 cp * 4 wg; 16 rows/block;
// per-thread 4 rows x 2 cols. x: LDS even/odd combined (8 KB). cas: L2 stream.
__global__ __launch_bounds__(128, 8) void kA(const float* __restrict__ x,
                                             const float* __restrict__ casAp,
                                             float* __restrict__ partial) {
    const int rb = blockIdx.x & 63;
    const int ks = blockIdx.x >> 6;
    const int rowbase = rb << 4;
    const int kbase = ks * KR_A;

    __shared__ float xc[64][2][16];   // [k][parity][row], 8 KB

    const int t  = threadIdx.x;
    const int cp = t & 31;            // cols c = 2cp, 2cp+1 (same parity)
    const int wg = t >> 5;            // rows wg*4 .. +3
    const int p  = cp >> 4;           // 0: even m (sum), 1: odd m (diff)

    const int sr = t & 15, sq = t >> 4;   // staging: row, k-quad group

    float acc[4][2];
#pragma unroll
    for (int j = 0; j < 4; ++j) { acc[j][0] = 0.f; acc[j][1] = 0.f; }

    for (int ch = 0; ch < 2; ++ch) {
        const int k0 = kbase + ch * 64;
        __syncthreads();
#pragma unroll
        for (int it = 0; it < 2; ++it) {
            const int kq = it * 8 + sq;   // 0..15
            const float4 xa = *reinterpret_cast<const float4*>(
                &x[(size_t)(rowbase + sr) * N_FFT + k0 + kq * 4]);
            const float4 xb = *reinterpret_cast<const float4*>(
                &x[(size_t)(rowbase + sr) * N_FFT + k0 + kq * 4 + HALF]);
#pragma unroll
            for (int u = 0; u < 4; ++u) {
                const float a = reinterpret_cast<const float*>(&xa)[u];
                const float b = reinterpret_cast<const float*>(&xb)[u];
                xc[kq * 4 + u][0][sr] = a + b;
                xc[kq * 4 + u][1][sr] = a - b;
            }
        }
        __syncthreads();

        const float* casp = casAp + ((size_t)k0 << 6) + cp * 2;
#pragma unroll 8
        for (int k = 0; k < 64; ++k) {
            const float2 cv = *reinterpret_cast<const float2*>(casp + k * 64);
            const float4 xv = *reinterpret_cast<const float4*>(&xc[k][p][wg * 4]);
            const float xvv[4] = {xv.x, xv.y, xv.z, xv.w};
#pragma unroll
            for (int j = 0; j < 4; ++j) {
                acc[j][0] = fmaf(xvv[j], cv.x, acc[j][0]);
                acc[j][1] = fmaf(xvv[j], cv.y, acc[j][1]);
            }
        }
    }

#pragma unroll
    for (int j = 0; j < 4; ++j) {
        *reinterpret_cast<float2*>(
            &partial[((size_t)ks << 16) + (size_t)(rowbase + wg * 4 + j) * 64 + cp * 2]) =
            make_float2(acc[j][0], acc[j][1]);
    }
}

// reduce KS_A partials -> xh (un-permuting columns); grid 256 x 256
__global__ __launch_bounds__(256) void kR(const float* __restrict__ partial,
                                          float* __restrict__ xh) {
    const int idx = blockIdx.x * 256 + threadIdx.x;   // 0..65535
    const int r = idx >> 6, c = idx & 63;
    const int m = (c < 32) ? (2 * c) : (2 * (c - 32) + 1);
    float a0 = 0.f, a1 = 0.f, a2 = 0.f, a3 = 0.f;
#pragma unroll 4
    for (int sp = 0; sp < KS_A; sp += 4) {
        a0 += partial[((size_t)(sp + 0) << 16) + idx];
        a1 += partial[((size_t)(sp + 1) << 16) + idx];
        a2 += partial[((size_t)(sp + 2) << 16) + idx];
        a3 += partial[((size_t)(sp + 3) << 16) + idx];
    }
    xh[(r << 6) + m] = (a0 + a1) + (a2 + a3);
}

// Step B: lowT[m][b*64+o] = (1/N) * sum_i xh[b*64+i][m] * w[(o*64+i)*64+m]
__global__ __launch_bounds__(256) void kB(const float* __restrict__ xh,
                                          const float* __restrict__ w,
                                          float* __restrict__ lowT) {
    const int b  = blockIdx.x >> 4;
    const int og = blockIdx.x & 15;
    const int o  = og * 4 + (threadIdx.x >> 6);
    const int m  = threadIdx.x & 63;
    float a0 = 0.f, a1 = 0.f, a2 = 0.f, a3 = 0.f;
#pragma unroll 4
    for (int i = 0; i < 64; i += 4) {
        a0 = fmaf(xh[(size_t)((b * 64 + i + 0) << 6) + m], w[(size_t)((o * 64 + i + 0) << 6) + m], a0);
        a1 = fmaf(xh[(size_t)((b * 64 + i + 1) << 6) + m], w[(size_t)((o * 64 + i + 1) << 6) + m], a1);
        a2 = fmaf(xh[(size_t)((b * 64 + i + 2) << 6) + m], w[(size_t)((o * 64 + i + 2) << 6) + m], a2);
        a3 = fmaf(xh[(size_t)((b * 64 + i + 3) << 6) + m], w[(size_t)((o * 64 + i + 3) << 6) + m], a3);
    }
    lowT[(size_t)m * ROWS + b * 64 + o] = ((a0 + a1) + (a2 + a3)) * (1.0f / (float)N_FFT);
}

// Step C (half-symmetric): out[r][n] = Se+So, out[r][n+8192] = Se-So (n<8192)
// grid 2048 = 64 rb * 32 nb; block 256 = 64 nq * 4 wg (rows wave-uniform).
// per-thread 4 rows x 4 n x 2 halves.
__global__ __launch_bounds__(256, 6) void kC(const float* __restrict__ lowT,
                                             const float* __restrict__ casB,
                                             float* __restrict__ out) {
    const int nb = blockIdx.x & 31;
    const int rb = blockIdx.x >> 5;
    const int rowbase = rb << 4;
    const int n0 = nb << 8;           // 256 half-n per block

    const int t  = threadIdx.x;
    const int nq = t & 63;            // n = n0 + nq*4 .. +3
    const int wg = t >> 6;            // rows wg*4 .. +3 (uniform per wave)

    float se[4][4], so[4][4];
#pragma unroll
    for (int j = 0; j < 4; ++j)
#pragma unroll
        for (int q = 0; q < 4; ++q) { se[j][q] = 0.f; so[j][q] = 0.f; }

    const float* lp = lowT + rowbase + wg * 4;   // + m*1024 (wave-uniform addr)
    const float* cp = casB + n0 + nq * 4;        // + m*8192

#pragma unroll 2
    for (int m = 0; m < 64; m += 2) {
        const float4 le = *reinterpret_cast<const float4*>(lp + ((size_t)m << 10));
        const float4 lo = *reinterpret_cast<const float4*>(lp + ((size_t)(m + 1) << 10));
        const float4 ce = *reinterpret_cast<const float4*>(cp + ((size_t)m << 13));
        const float4 co = *reinterpret_cast<const float4*>(cp + ((size_t)(m + 1) << 13));
        const float lev[4] = {le.x, le.y, le.z, le.w};
        const float lov[4] = {lo.x, lo.y, lo.z, lo.w};
        const float cev[4] = {ce.x, ce.y, ce.z, ce.w};
        const float cov[4] = {co.x, co.y, co.z, co.w};
#pragma unroll
        for (int j = 0; j < 4; ++j)
#pragma unroll
            for (int q = 0; q < 4; ++q) {
                se[j][q] = fmaf(lev[j], cev[q], se[j][q]);
                so[j][q] = fmaf(lov[j], cov[q], so[j][q]);
            }
    }

#pragma unroll
    for (int j = 0; j < 4; ++j) {
        const size_t row = (size_t)rowbase + wg * 4 + j;
        *reinterpret_cast<float4*>(&out[row * N_FFT + n0 + nq * 4]) =
            make_float4(se[j][0] + so[j][0], se[j][1] + so[j][1],
                        se[j][2] + so[j][2], se[j][3] + so[j][3]);
        *reinterpret_cast<float4*>(&out[row * N_FFT + HALF + n0 + nq * 4]) =
            make_float4(se[j][0] - so[j][0], se[j][1] - so[j][1],
                        se[j][2] - so[j][2], se[j][3] - so[j][3]);
    }
}

extern "C" void kernel_launch(void* const* d_in, const int* in_sizes, int n_in,
                              void* d_out, int out_size, void* d_ws, size_t ws_size,
                              hipStream_t stream) {
    const float* x = (const float*)d_in[0];
    const float* w = (const float*)d_in[1];
    float* out = (float*)d_out;
    float* ws  = (float*)d_ws;

    float* castab  = ws;
    float* casAp   = ws + 16384;
    float* casB    = ws + 540672;
    float* partial = ws + 1064960;
    float* xh      = ws + 5259264;
    float* lowT    = ws + 5324800;

    k_tab<<<64, 256, 0, stream>>>(castab);
    k_fill<<<4096, 256, 0, stream>>>(castab, casAp, casB);
    kA<<<4096, 128, 0, stream>>>(x, casAp, partial);
    kR<<<256, 256, 0, stream>>>(partial, xh);
    kB<<<256, 256, 0, stream>>>(xh, w, lowT);
    kC<<<2048, 256, 0, stream>>>(lowT, casB, out);
}

// Round 7
// 77.006 us; speedup vs baseline: 1.3667x; 1.3667x over previous
//
#include <hip/hip_runtime.h>
#include <math.h>

#define N_FFT 16384
#define HALF 8192
#define ROWS 1024    // B*Cin = B*Cout = 16*64
#define KS_A 64      // k-splits of the 8192 half-space
#define KR_A 128     // half-k per kA block
#define CHUNK 32     // half-k per LDS stage

// ---------------- ws layout (float offsets) ----------------
// castab @0 [16384]
// casAp  @16384  [8192*64]  (perm cols: c<32 -> m=2c (even), c>=32 -> m=2(c-32)+1 (odd))
// casB   @540672 [64*8192]
// partial@1064960 [64*65536]
// xh     @5259264 [65536]
// lowT   @5324800 [65536]

__global__ __launch_bounds__(256) void k_tab(float* __restrict__ castab) {
    int i = blockIdx.x * 256 + threadIdx.x;
    if (i < N_FFT) {
        double ang = 6.283185307179586476925287 * (double)i / (double)N_FFT;
        castab[i] = (float)(cos(ang) + sin(ang));
    }
}

__global__ __launch_bounds__(256) void k_fill(const float* __restrict__ castab,
                                              float* __restrict__ casAp,
                                              float* __restrict__ casB) {
    int tid = blockIdx.x * 256 + threadIdx.x;    // 0 .. 2^20-1
    if (tid < (1 << 19)) {
        int n = tid >> 6, c = tid & 63;
        int m = (c < 32) ? (2 * c) : (2 * (c - 32) + 1);
        casAp[tid] = castab[(n * m) & (N_FFT - 1)];
    } else {
        int t2 = tid - (1 << 19);                // 0 .. 2^19-1
        int m = t2 >> 13, n = t2 & (HALF - 1);
        casB[t2] = castab[(m * n) & (N_FFT - 1)];
    }
}

// Step A (half-symmetric): partial[ks][r][c] = sum_k (x[r][k] +- x[r][k+8192]) * casAp[k][c]
// grid 512 = 8 rb * 64 ks; block 512 = 8 waves.
// Wave: 8 cas-cols (wave-uniform -> s_load, SGPR fma operand), parity = wq>>2.
// Lane: 2 rows (128 rows/block) via ds_read_b64 from swizzled halfsum tile.
__global__ __launch_bounds__(512, 4) void kA(const float* __restrict__ x,
                                             const float* __restrict__ casAp,
                                             float* __restrict__ partial) {
    const int rb = blockIdx.x & 7;
    const int ks = blockIdx.x >> 3;
    const int rowbase = rb << 7;
    const int kbase = ks * KR_A;

    __shared__ float xs[CHUNK][2][128];   // [k][parity][row-swizzled], 32 KB

    const int t   = threadIdx.x;
    const int wq  = __builtin_amdgcn_readfirstlane(t >> 6);  // 0..7, uniform
    const int lam = t & 63;
    const int c0  = wq * 8;               // col octet (pure parity)
    const int p   = wq >> 2;              // 0: even m (sum), 1: odd m (diff)
    const int r2  = lam * 2;              // local row pair

    float acc[2][8];
#pragma unroll
    for (int i = 0; i < 2; ++i)
#pragma unroll
        for (int j = 0; j < 8; ++j) acc[i][j] = 0.f;

    for (int ch = 0; ch < KR_A / CHUNK; ++ch) {
        const int k0 = kbase + ch * CHUNK;
        if (ch) __syncthreads();
        // stage halfsums: 128 rows x 32 k -> 1024 float4-units, 2 passes of 512
#pragma unroll
        for (int it = 0; it < 2; ++it) {
            const int idx = it * 512 + t;
            const int r = idx >> 3, kq = idx & 7;
            const float4 a4 = *reinterpret_cast<const float4*>(
                &x[(size_t)(rowbase + r) * N_FFT + k0 + kq * 4]);
            const float4 b4 = *reinterpret_cast<const float4*>(
                &x[(size_t)(rowbase + r) * N_FFT + k0 + kq * 4 + HALF]);
            const int rsw = r ^ (kq << 1);
#pragma unroll
            for (int u = 0; u < 4; ++u) {
                const float a = reinterpret_cast<const float*>(&a4)[u];
                const float b = reinterpret_cast<const float*>(&b4)[u];
                xs[kq * 4 + u][0][rsw] = a + b;
                xs[kq * 4 + u][1][rsw] = a - b;
            }
        }
        __syncthreads();

        const float* cw = casAp + ((size_t)k0 << 6) + c0;   // uniform
#pragma unroll 4
        for (int k = 0; k < CHUNK; ++k) {
            const int rd = r2 ^ ((k >> 2) << 1);
            const float2 xv = *reinterpret_cast<const float2*>(&xs[k][p][rd]);
            float cv[8];
#pragma unroll
            for (int j = 0; j < 8; ++j) cv[j] = cw[k * 64 + j];
#pragma unroll
            for (int j = 0; j < 8; ++j) {
                acc[0][j] = fmaf(xv.x, cv[j], acc[0][j]);
                acc[1][j] = fmaf(xv.y, cv[j], acc[1][j]);
            }
        }
    }

#pragma unroll
    for (int i = 0; i < 2; ++i) {
        float* pp = &partial[((size_t)ks << 16) +
                             (size_t)(rowbase + r2 + i) * 64 + c0];
        *reinterpret_cast<float4*>(pp) =
            make_float4(acc[i][0], acc[i][1], acc[i][2], acc[i][3]);
        *reinterpret_cast<float4*>(pp + 4) =
            make_float4(acc[i][4], acc[i][5], acc[i][6], acc[i][7]);
    }
}

// reduce KS_A partials -> xh (un-permuting columns); grid 256 x 256
__global__ __launch_bounds__(256) void kR(const float* __restrict__ partial,
                                          float* __restrict__ xh) {
    const int idx = blockIdx.x * 256 + threadIdx.x;   // 0..65535
    const int r = idx >> 6, c = idx & 63;
    const int m = (c < 32) ? (2 * c) : (2 * (c - 32) + 1);
    float a0 = 0.f, a1 = 0.f, a2 = 0.f, a3 = 0.f;
#pragma unroll 4
    for (int sp = 0; sp < KS_A; sp += 4) {
        a0 += partial[((size_t)(sp + 0) << 16) + idx];
        a1 += partial[((size_t)(sp + 1) << 16) + idx];
        a2 += partial[((size_t)(sp + 2) << 16) + idx];
        a3 += partial[((size_t)(sp + 3) << 16) + idx];
    }
    xh[(r << 6) + m] = (a0 + a1) + (a2 + a3);
}

// Step B: lowT[m][b*64+o] = (1/N) * sum_i xh[b*64+i][m] * w[(o*64+i)*64+m]
__global__ __launch_bounds__(256) void kB(const float* __restrict__ xh,
                                          const float* __restrict__ w,
                                          float* __restrict__ lowT) {
    const int b  = blockIdx.x >> 4;
    const int og = blockIdx.x & 15;
    const int o  = og * 4 + (threadIdx.x >> 6);
    const int m  = threadIdx.x & 63;
    float a0 = 0.f, a1 = 0.f, a2 = 0.f, a3 = 0.f;
#pragma unroll 4
    for (int i = 0; i < 64; i += 4) {
        a0 = fmaf(xh[(size_t)((b * 64 + i + 0) << 6) + m], w[(size_t)((o * 64 + i + 0) << 6) + m], a0);
        a1 = fmaf(xh[(size_t)((b * 64 + i + 1) << 6) + m], w[(size_t)((o * 64 + i + 1) << 6) + m], a1);
        a2 = fmaf(xh[(size_t)((b * 64 + i + 2) << 6) + m], w[(size_t)((o * 64 + i + 2) << 6) + m], a2);
        a3 = fmaf(xh[(size_t)((b * 64 + i + 3) << 6) + m], w[(size_t)((o * 64 + i + 3) << 6) + m], a3);
    }
    lowT[(size_t)m * ROWS + b * 64 + o] = ((a0 + a1) + (a2 + a3)) * (1.0f / (float)N_FFT);
}

// Step C (half-symmetric): out[r][n] = Se+So, out[r][n+8192] = Se-So (n<8192)
// grid 1024 = 32 rb * 32 nb; block 256 = 4 waves.
// Wave: 8 rows (wave-uniform -> lowT via s_load). Lane: 4 n (casB float4 stream).
__global__ __launch_bounds__(256, 4) void kC(const float* __restrict__ lowT,
                                             const float* __restrict__ casB,
                                             float* __restrict__ out) {
    const int rb = blockIdx.x >> 5;
    const int nb = blockIdx.x & 31;
    const int t  = threadIdx.x;
    const int wq = __builtin_amdgcn_readfirstlane(t >> 6);   // 0..3, uniform
    const int r0 = rb * 32 + wq * 8;                          // wave-uniform rows
    const int n  = (nb << 8) + (t & 63) * 4;

    float se[8][4], so[8][4];
#pragma unroll
    for (int j = 0; j < 8; ++j)
#pragma unroll
        for (int q = 0; q < 4; ++q) { se[j][q] = 0.f; so[j][q] = 0.f; }

#pragma unroll 2
    for (int m = 0; m < 64; m += 2) {
        const float* lpe = lowT + ((size_t)m << 10) + r0;        // uniform
        const float* lpo = lpe + ROWS;
        const float4 ce = *reinterpret_cast<const float4*>(&casB[((size_t)m << 13) + n]);
        const float4 co = *reinterpret_cast<const float4*>(&casB[((size_t)(m + 1) << 13) + n]);
        const float cev[4] = {ce.x, ce.y, ce.z, ce.w};
        const float cov[4] = {co.x, co.y, co.z, co.w};
#pragma unroll
        for (int j = 0; j < 8; ++j) {
            const float le = lpe[j];
            const float lo = lpo[j];
#pragma unroll
            for (int q = 0; q < 4; ++q) {
                se[j][q] = fmaf(le, cev[q], se[j][q]);
                so[j][q] = fmaf(lo, cov[q], so[j][q]);
            }
        }
    }

#pragma unroll
    for (int j = 0; j < 8; ++j) {
        const size_t row = (size_t)r0 + j;
        *reinterpret_cast<float4*>(&out[row * N_FFT + n]) =
            make_float4(se[j][0] + so[j][0], se[j][1] + so[j][1],
                        se[j][2] + so[j][2], se[j][3] + so[j][3]);
        *reinterpret_cast<float4*>(&out[row * N_FFT + HALF + n]) =
            make_float4(se[j][0] - so[j][0], se[j][1] - so[j][1],
                        se[j][2] - so[j][2], se[j][3] - so[j][3]);
    }
}

extern "C" void kernel_launch(void* const* d_in, const int* in_sizes, int n_in,
                              void* d_out, int out_size, void* d_ws, size_t ws_size,
                              hipStream_t stream) {
    const float* x = (const float*)d_in[0];
    const float* w = (const float*)d_in[1];
    float* out = (float*)d_out;
    float* ws  = (float*)d_ws;

    float* castab  = ws;
    float* casAp   = ws + 16384;
    float* casB    = ws + 540672;
    float* partial = ws + 1064960;
    float* xh      = ws + 5259264;
    float* lowT    = ws + 5324800;

    k_tab<<<64, 256, 0, stream>>>(castab);
    k_fill<<<4096, 256, 0, stream>>>(castab, casAp, casB);
    kA<<<512, 512, 0, stream>>>(x, casAp, partial);
    kR<<<256, 256, 0, stream>>>(partial, xh);
    kB<<<256, 256, 0, stream>>>(xh, w, lowT);
    kC<<<1024, 256, 0, stream>>>(lowT, casB, out);
}

// Round 8
// 66.856 us; speedup vs baseline: 1.5743x; 1.1518x over previous
//
#include <hip/hip_runtime.h>
#include <math.h>

#define N_FFT 16384
#define HALF 8192
#define ROWS 1024    // B*Cin = B*Cout = 16*64
#define KS_A 64      // k-splits of the 8192 half-space
#define KR_A 128     // half-k per kA block
#define CHUNK 32     // half-k per LDS stage
#define NMASK 16383

// ---------------- ws layout (float offsets) ----------------
// castab @0      [16384]   cas(2*pi*i/N)
// costab @16384  [16384]   2*cos(2*pi*i/N)
// partial@32768  [64*65536]
// xh     @4227072 [65536]
// lowT   @4292608 [65536]

__global__ __launch_bounds__(256) void k_tab(float* __restrict__ castab,
                                             float* __restrict__ costab) {
    int i = blockIdx.x * 256 + threadIdx.x;   // grid 64*256 = 16384 exactly
    double ang = 6.283185307179586476925287 * (double)i / (double)N_FFT;
    double c = cos(ang), s = sin(ang);
    castab[i] = (float)(c + s);
    costab[i] = (float)(2.0 * c);
}

// Step A (half-symmetric + cas recurrence):
//   partial[ks][r][c] = sum_{k in split} (x[r][k] +- x[r][k+8192]) * cas(k*m_c*theta)
// grid 512 = 8 rb * 64 ks; block 512 = 8 waves; wave = 8 m-cols (single parity),
// lane = 2 rows. cas generated in-register: 8 oscillators/lane, init from table
// at kbase (<=128 recurrence steps). No cas memory traffic in the loop.
__global__ __launch_bounds__(512, 4) void kA(const float* __restrict__ x,
                                             const float* __restrict__ castab,
                                             const float* __restrict__ costab,
                                             float* __restrict__ partial) {
    const int rb = blockIdx.x & 7;
    const int ks = blockIdx.x >> 3;
    const int rowbase = rb << 7;
    const int kbase = ks * KR_A;

    __shared__ float xs[CHUNK][2][128];   // [k][parity][row-swizzled], 32 KB

    const int t   = threadIdx.x;
    const int wq  = __builtin_amdgcn_readfirstlane(t >> 6);  // 0..7, uniform
    const int lam = t & 63;
    const int c0  = wq * 8;               // permuted col octet (single parity)
    const int p   = wq >> 2;              // 0: even m (sum), 1: odd m (diff)
    const int r2  = lam * 2;              // local row pair
    const int mbase = (wq < 4) ? (wq << 4) : (((wq - 4) << 4) + 1);

    float k2[8], cA[8], cB[8];
#pragma unroll
    for (int j = 0; j < 8; ++j) {
        const int m = mbase + 2 * j;
        k2[j] = costab[m];                              // 2*cos(m*theta)
        cB[j] = castab[((kbase - 1) * m) & NMASK];      // cas((kbase-1)*m)
        cA[j] = castab[(kbase * m) & NMASK];            // cas(kbase*m)
    }

    float acc0[8], acc1[8];
#pragma unroll
    for (int j = 0; j < 8; ++j) { acc0[j] = 0.f; acc1[j] = 0.f; }

    for (int ch = 0; ch < KR_A / CHUNK; ++ch) {
        const int k0 = kbase + ch * CHUNK;
        if (ch) __syncthreads();
        // stage halfsums: 128 rows x 32 k
#pragma unroll
        for (int it = 0; it < 2; ++it) {
            const int idx = it * 512 + t;
            const int r = idx >> 3, kq = idx & 7;
            const float4 a4 = *reinterpret_cast<const float4*>(
                &x[(size_t)(rowbase + r) * N_FFT + k0 + kq * 4]);
            const float4 b4 = *reinterpret_cast<const float4*>(
                &x[(size_t)(rowbase + r) * N_FFT + k0 + kq * 4 + HALF]);
            const int rsw = r ^ (kq << 1);
#pragma unroll
            for (int u = 0; u < 4; ++u) {
                const float a = reinterpret_cast<const float*>(&a4)[u];
                const float b = reinterpret_cast<const float*>(&b4)[u];
                xs[kq * 4 + u][0][rsw] = a + b;
                xs[kq * 4 + u][1][rsw] = a - b;
            }
        }
        __syncthreads();

        for (int k = 0; k < CHUNK; k += 2) {
            {   // step k: current = cA; then cB <- c_{k+1}
                const int rd = r2 ^ ((k >> 2) << 1);
                const float2 s2 = *reinterpret_cast<const float2*>(&xs[k][p][rd]);
#pragma unroll
                for (int j = 0; j < 8; ++j) {
                    acc0[j] = fmaf(s2.x, cA[j], acc0[j]);
                    acc1[j] = fmaf(s2.y, cA[j], acc1[j]);
                    cB[j] = fmaf(k2[j], cA[j], -cB[j]);
                }
            }
            {   // step k+1: current = cB; then cA <- c_{k+2}
                const int rd = r2 ^ (((k + 1) >> 2) << 1);
                const float2 s2 = *reinterpret_cast<const float2*>(&xs[k + 1][p][rd]);
#pragma unroll
                for (int j = 0; j < 8; ++j) {
                    acc0[j] = fmaf(s2.x, cB[j], acc0[j]);
                    acc1[j] = fmaf(s2.y, cB[j], acc1[j]);
                    cA[j] = fmaf(k2[j], cB[j], -cA[j]);
                }
            }
        }
    }

#pragma unroll
    for (int i = 0; i < 2; ++i) {
        float* pp = &partial[((size_t)ks << 16) +
                             (size_t)(rowbase + r2 + i) * 64 + c0];
        const float* a = i ? acc1 : acc0;
        *reinterpret_cast<float4*>(pp) =
            make_float4(a[0], a[1], a[2], a[3]);
        *reinterpret_cast<float4*>(pp + 4) =
            make_float4(a[4], a[5], a[6], a[7]);
    }
}

// reduce KS_A partials -> xh (un-permuting columns); grid 256 x 256
__global__ __launch_bounds__(256) void kR(const float* __restrict__ partial,
                                          float* __restrict__ xh) {
    const int idx = blockIdx.x * 256 + threadIdx.x;   // 0..65535
    const int r = idx >> 6, c = idx & 63;
    const int m = (c < 32) ? (2 * c) : (2 * (c - 32) + 1);
    float a0 = 0.f, a1 = 0.f, a2 = 0.f, a3 = 0.f;
#pragma unroll 4
    for (int sp = 0; sp < KS_A; sp += 4) {
        a0 += partial[((size_t)(sp + 0) << 16) + idx];
        a1 += partial[((size_t)(sp + 1) << 16) + idx];
        a2 += partial[((size_t)(sp + 2) << 16) + idx];
        a3 += partial[((size_t)(sp + 3) << 16) + idx];
    }
    xh[(r << 6) + m] = (a0 + a1) + (a2 + a3);
}

// Step B: lowT[m][b*64+o] = (1/N) * sum_i xh[b*64+i][m] * w[(o*64+i)*64+m]
__global__ __launch_bounds__(256) void kB(const float* __restrict__ xh,
                                          const float* __restrict__ w,
                                          float* __restrict__ lowT) {
    const int b  = blockIdx.x >> 4;
    const int og = blockIdx.x & 15;
    const int o  = og * 4 + (threadIdx.x >> 6);
    const int m  = threadIdx.x & 63;
    float a0 = 0.f, a1 = 0.f, a2 = 0.f, a3 = 0.f;
#pragma unroll 4
    for (int i = 0; i < 64; i += 4) {
        a0 = fmaf(xh[(size_t)((b * 64 + i + 0) << 6) + m], w[(size_t)((o * 64 + i + 0) << 6) + m], a0);
        a1 = fmaf(xh[(size_t)((b * 64 + i + 1) << 6) + m], w[(size_t)((o * 64 + i + 1) << 6) + m], a1);
        a2 = fmaf(xh[(size_t)((b * 64 + i + 2) << 6) + m], w[(size_t)((o * 64 + i + 2) << 6) + m], a2);
        a3 = fmaf(xh[(size_t)((b * 64 + i + 3) << 6) + m], w[(size_t)((o * 64 + i + 3) << 6) + m], a3);
    }
    lowT[(size_t)m * ROWS + b * 64 + o] = ((a0 + a1) + (a2 + a3)) * (1.0f / (float)N_FFT);
}

// Step C (half-symmetric + cas recurrence):
//   out[r][n] = Se+So, out[r][n+8192] = Se-So (n<8192)
// grid 2048 = 16 rb * 128 nb; block 256 = 4 waves; wave = 16 rows (uniform ->
// lowT via s_load), lane = 1 n. cas(m*n*theta) generated by 1 oscillator/lane.
// Inner loop has ZERO vector memory ops.
__global__ __launch_bounds__(256, 4) void kC(const float* __restrict__ lowT,
                                             const float* __restrict__ castab,
                                             const float* __restrict__ costab,
                                             float* __restrict__ out) {
    const int nb = blockIdx.x & 127;
    const int rb = blockIdx.x >> 7;
    const int t  = threadIdx.x;
    const int wq = __builtin_amdgcn_readfirstlane(t >> 6);   // 0..3, uniform
    const int r0 = rb * 64 + wq * 16;                        // wave-uniform rows
    const int n  = (nb << 6) + (t & 63);                     // 0..8191

    const float k2 = costab[n];   // 2*cos(n*theta)
    float ce = 1.0f;              // cas(0)
    float co = castab[n];         // cas(n*theta)

    float se[16], so[16];
#pragma unroll
    for (int j = 0; j < 16; ++j) { se[j] = 0.f; so[j] = 0.f; }

#pragma unroll 2
    for (int g = 0; g < 32; ++g) {
        const float* le = lowT + ((size_t)(2 * g) << 10) + r0;   // uniform addr
        const float* lo = le + ROWS;
#pragma unroll
        for (int j = 0; j < 16; ++j) {
            se[j] = fmaf(ce, le[j], se[j]);
            so[j] = fmaf(co, lo[j], so[j]);
        }
        ce = fmaf(k2, co, -ce);   // cas((2g+2)*n)
        co = fmaf(k2, ce, -co);   // cas((2g+3)*n)
    }

#pragma unroll
    for (int j = 0; j < 16; ++j) {
        const size_t row = (size_t)r0 + j;
        out[row * N_FFT + n]        = se[j] + so[j];
        out[row * N_FFT + HALF + n] = se[j] - so[j];
    }
}

extern "C" void kernel_launch(void* const* d_in, const int* in_sizes, int n_in,
                              void* d_out, int out_size, void* d_ws, size_t ws_size,
                              hipStream_t stream) {
    const float* x = (const float*)d_in[0];
    const float* w = (const float*)d_in[1];
    float* out = (float*)d_out;
    float* ws  = (float*)d_ws;

    float* castab  = ws;
    float* costab  = ws + 16384;
    float* partial = ws + 32768;
    float* xh      = ws + 4227072;
    float* lowT    = ws + 4292608;

    k_tab<<<64, 256, 0, stream>>>(castab, costab);
    kA<<<512, 512, 0, stream>>>(x, castab, costab, partial);
    kR<<<256, 256, 0, stream>>>(partial, xh);
    kB<<<256, 256, 0, stream>>>(xh, w, lowT);
    kC<<<2048, 256, 0, stream>>>(lowT, castab, costab, out);
}